// Round 1
// baseline (799.781 us; speedup 1.0000x reference)
//
#include <hip/hip_runtime.h>
#include <hip/hip_bf16.h>
#include <math.h>

// Problem constants (match reference)
constexpr int H  = 128;   // hidden
constexpr int B  = 512;   // graphs
constexpr int CHUNK = 64; // rows per wave in the streaming kernel
// Workspace layout per rank (floats):
//   [0,65536)        sum   [B][H]
//   [65536,131072)   gsum  [B][H]
//   [131072,196608)  max   [B][H]
//   [196608,197120)  cnt   [B]
constexpr int RANK_STRIDE = 3 * B * H + B;  // 197120 floats
constexpr int TOTAL_WS    = 3 * RANK_STRIDE;

__device__ __forceinline__ float atomicMaxF(float* addr, float val) {
  // classic bit trick: int-max for >=0, uint-min for <0; buffer init to -inf
  if (val >= 0.f) {
    return __int_as_float(atomicMax((int*)addr, __float_as_int(val)));
  } else {
    return __uint_as_float(atomicMin((unsigned int*)addr, __float_as_uint(val)));
  }
}

__global__ __launch_bounds__(256) void init_ws_kernel(float* ws) {
  int i = blockIdx.x * blockDim.x + threadIdx.x;
  if (i >= TOTAL_WS) return;
  int o = i % RANK_STRIDE;
  bool ismax = (o >= 2 * B * H) && (o < 3 * B * H);
  ws[i] = ismax ? __int_as_float(0xFF800000) : 0.0f;  // -inf for max, 0 else
}

// One wave processes CHUNK contiguous rows. Each lane owns 2 columns
// (2*lane, 2*lane+1) -> float2 loads = 512B/row/wave, fully coalesced.
// Segment accumulators live in registers; flush with atomics on boundary.
__global__ __launch_bounds__(256) void rank_kernel(
    const float* __restrict__ h, const int* __restrict__ b,
    const float* __restrict__ Wg, const float* __restrict__ bg,
    float* __restrict__ sumb, float* __restrict__ gsumb,
    float* __restrict__ maxb, float* __restrict__ cntb, int N)
{
  const int lane = threadIdx.x & 63;
  const int wave = threadIdx.x >> 6;
  const long long gw = (long long)blockIdx.x * 4 + wave;
  const int row0 = (int)(gw * CHUNK);
  if (row0 >= N) return;
  const int row1 = min(N, row0 + CHUNK);

  const float2 wg = ((const float2*)Wg)[lane];
  const float bgv = bg[0];

  float s0 = 0.f, s1 = 0.f, g0 = 0.f, g1 = 0.f;
  float m0 = -INFINITY, m1 = -INFINITY;
  int cnt = 0;
  int cur = b[row0];

  for (int r = row0; r < row1; ++r) {
    const int seg = b[r];                       // wave-uniform (broadcast)
    const float2 hv = ((const float2*)h)[(long long)r * 64 + lane];
    if (seg != cur) {                           // uniform branch
      const int base = cur * H + 2 * lane;
      atomicAdd(sumb + base,     s0); atomicAdd(sumb + base + 1,  s1);
      atomicAdd(gsumb + base,    g0); atomicAdd(gsumb + base + 1, g1);
      atomicMaxF(maxb + base,    m0); atomicMaxF(maxb + base + 1, m1);
      if (lane == 0) atomicAdd(cntb + cur, (float)cnt);
      s0 = s1 = g0 = g1 = 0.f; m0 = m1 = -INFINITY; cnt = 0; cur = seg;
    }
    // gate = sigmoid(h . Wg + bg): 64-lane butterfly reduce
    float part = hv.x * wg.x + hv.y * wg.y;
    part += __shfl_xor(part, 1);
    part += __shfl_xor(part, 2);
    part += __shfl_xor(part, 4);
    part += __shfl_xor(part, 8);
    part += __shfl_xor(part, 16);
    part += __shfl_xor(part, 32);
    const float gate = 1.0f / (1.0f + __expf(-(part + bgv)));

    s0 += hv.x;                 s1 += hv.y;
    g0 = fmaf(gate, hv.x, g0);  g1 = fmaf(gate, hv.y, g1);
    m0 = fmaxf(m0, hv.x);       m1 = fmaxf(m1, hv.y);
    ++cnt;
  }
  if (cnt > 0) {
    const int base = cur * H + 2 * lane;
    atomicAdd(sumb + base,     s0); atomicAdd(sumb + base + 1,  s1);
    atomicAdd(gsumb + base,    g0); atomicAdd(gsumb + base + 1, g1);
    atomicMaxF(maxb + base,    m0); atomicMaxF(maxb + base + 1, m1);
    if (lane == 0) atomicAdd(cntb + cur, (float)cnt);
  }
}

__device__ __forceinline__ float siluf(float x) {
  return x / (1.0f + __expf(-x));
}

// 128 threads, 4 graphs per block (grid = B/4 = 128).
// Phase A (per rank): build agg[4][512] in LDS, r = agg @ Wp + bp -> state.
// Phase B: LayerNorm(384) + SiLU per graph. Phase C: FC1(384->128)+SiLU,
// FC2(128->1) with weight loads shared across the 4 graphs.
__global__ __launch_bounds__(128) void finalize_kernel(
    const float* __restrict__ ws,
    const float* __restrict__ Wp0, const float* __restrict__ bp0,
    const float* __restrict__ Wp1, const float* __restrict__ bp1,
    const float* __restrict__ Wp2, const float* __restrict__ bp2,
    const float* __restrict__ gamma, const float* __restrict__ beta,
    const float* __restrict__ W1, const float* __restrict__ b1f,
    const float* __restrict__ W2, const float* __restrict__ b2f,
    float* __restrict__ out)
{
  __shared__ float aggL[4][4 * H];   // 8 KB
  __shared__ float state[4][3 * H];  // 6 KB
  __shared__ float red[8];

  const int j = threadIdx.x;         // 0..127
  const int lane = j & 63;
  const int wv = j >> 6;             // 0..1
  const int gbase = blockIdx.x * 4;

  const float* Wp[3] = {Wp0, Wp1, Wp2};
  const float* bp[3] = {bp0, bp1, bp2};

  for (int k = 0; k < 3; ++k) {
    const float* sumb  = ws + k * RANK_STRIDE;
    const float* gsumb = sumb + B * H;
    const float* maxb  = sumb + 2 * B * H;
    const float* cntb  = sumb + 3 * B * H;

    for (int g = 0; g < 4; ++g) {
      const int bidx = gbase + g;
      const float c  = cntb[bidx];
      const float cm = fmaxf(c, 1.0f);
      const float sv = sumb[bidx * H + j];
      const float mv = maxb[bidx * H + j];
      const float gv = gsumb[bidx * H + j];
      aggL[g][j]         = sv;
      aggL[g][H + j]     = sv / cm;
      aggL[g][2 * H + j] = (c > 0.f) ? mv : 0.f;
      aggL[g][3 * H + j] = gv;
    }
    __syncthreads();

    const float bpv = bp[k][j];
    float r0 = bpv, r1 = bpv, r2 = bpv, r3 = bpv;
    const float* W = Wp[k];
    for (int i = 0; i < 4 * H; ++i) {
      const float w = W[i * H + j];        // coalesced; L2-resident
      r0 = fmaf(aggL[0][i], w, r0);        // LDS broadcast reads
      r1 = fmaf(aggL[1][i], w, r1);
      r2 = fmaf(aggL[2][i], w, r2);
      r3 = fmaf(aggL[3][i], w, r3);
    }
    state[0][k * H + j] = r0;
    state[1][k * H + j] = r1;
    state[2][k * H + j] = r2;
    state[3][k * H + j] = r3;
    __syncthreads();
  }

  // LayerNorm + SiLU per graph (384 elems, 3 per thread)
  for (int g = 0; g < 4; ++g) {
    const float v0 = state[g][j];
    const float v1 = state[g][H + j];
    const float v2 = state[g][2 * H + j];
    float ps = v0 + v1 + v2;
    float pq = v0 * v0 + v1 * v1 + v2 * v2;
    for (int m = 1; m < 64; m <<= 1) {
      ps += __shfl_xor(ps, m);
      pq += __shfl_xor(pq, m);
    }
    if (lane == 0) { red[wv * 2] = ps; red[wv * 2 + 1] = pq; }
    __syncthreads();
    const float ts = red[0] + red[2];
    const float tq = red[1] + red[3];
    const float mu  = ts * (1.0f / 384.0f);
    const float var = tq * (1.0f / 384.0f) - mu * mu;
    const float inv = rsqrtf(var + 1e-5f);
    float x0 = (v0 - mu) * inv * gamma[j]         + beta[j];
    float x1 = (v1 - mu) * inv * gamma[H + j]     + beta[H + j];
    float x2 = (v2 - mu) * inv * gamma[2 * H + j] + beta[2 * H + j];
    state[g][j]         = siluf(x0);
    state[g][H + j]     = siluf(x1);
    state[g][2 * H + j] = siluf(x2);
    __syncthreads();
  }

  // FC1: x = silu(state @ W1 + b1f); weight load shared across 4 graphs
  const float b1v = b1f[j];
  float a0 = b1v, a1 = b1v, a2 = b1v, a3 = b1v;
  for (int i = 0; i < 3 * H; ++i) {
    const float w = W1[i * H + j];
    a0 = fmaf(state[0][i], w, a0);
    a1 = fmaf(state[1][i], w, a1);
    a2 = fmaf(state[2][i], w, a2);
    a3 = fmaf(state[3][i], w, a3);
  }
  a0 = siluf(a0); a1 = siluf(a1); a2 = siluf(a2); a3 = siluf(a3);

  // FC2: dot over 128
  const float w2 = W2[j];
  float p0 = a0 * w2, p1 = a1 * w2, p2 = a2 * w2, p3 = a3 * w2;
  for (int m = 1; m < 64; m <<= 1) {
    p0 += __shfl_xor(p0, m);
    p1 += __shfl_xor(p1, m);
    p2 += __shfl_xor(p2, m);
    p3 += __shfl_xor(p3, m);
  }
  __syncthreads();  // red[] reuse
  if (lane == 0) {
    red[wv * 4 + 0] = p0; red[wv * 4 + 1] = p1;
    red[wv * 4 + 2] = p2; red[wv * 4 + 3] = p3;
  }
  __syncthreads();
  if (j < 4) out[gbase + j] = red[j] + red[4 + j] + b2f[0];
}

extern "C" void kernel_launch(void* const* d_in, const int* in_sizes, int n_in,
                              void* d_out, int out_size, void* d_ws, size_t ws_size,
                              hipStream_t stream) {
  const float* h0  = (const float*)d_in[0];
  const float* h1  = (const float*)d_in[1];
  const float* h2  = (const float*)d_in[2];
  const int*   b0  = (const int*)d_in[3];
  const int*   b1  = (const int*)d_in[4];
  const int*   b2  = (const int*)d_in[5];
  const float* Wg0 = (const float*)d_in[6];
  const float* bg0 = (const float*)d_in[7];
  const float* Wg1 = (const float*)d_in[8];
  const float* bg1 = (const float*)d_in[9];
  const float* Wg2 = (const float*)d_in[10];
  const float* bg2 = (const float*)d_in[11];
  const float* Wp0 = (const float*)d_in[12];
  const float* bp0 = (const float*)d_in[13];
  const float* Wp1 = (const float*)d_in[14];
  const float* bp1 = (const float*)d_in[15];
  const float* Wp2 = (const float*)d_in[16];
  const float* bp2 = (const float*)d_in[17];
  const float* gamma = (const float*)d_in[18];
  const float* beta  = (const float*)d_in[19];
  const float* W1  = (const float*)d_in[20];
  const float* b1f = (const float*)d_in[21];
  const float* W2  = (const float*)d_in[22];
  const float* b2f = (const float*)d_in[23];

  const int N0 = in_sizes[3];
  const int N1 = in_sizes[4];
  const int N2 = in_sizes[5];

  float* ws = (float*)d_ws;
  float* s0 = ws;
  float* s1 = ws + RANK_STRIDE;
  float* s2 = ws + 2 * RANK_STRIDE;

  // init workspace (sums/cnt = 0, max = -inf)
  {
    int blocks = (TOTAL_WS + 255) / 256;
    hipLaunchKernelGGL(init_ws_kernel, dim3(blocks), dim3(256), 0, stream, ws);
  }

  // streaming rank kernels: 256 rows per block (64/wave)
  {
    int blocks = (N0 + 255) / 256;
    hipLaunchKernelGGL(rank_kernel, dim3(blocks), dim3(256), 0, stream,
                       h0, b0, Wg0, bg0,
                       s0, s0 + B * H, s0 + 2 * B * H, s0 + 3 * B * H, N0);
  }
  {
    int blocks = (N1 + 255) / 256;
    hipLaunchKernelGGL(rank_kernel, dim3(blocks), dim3(256), 0, stream,
                       h1, b1, Wg1, bg1,
                       s1, s1 + B * H, s1 + 2 * B * H, s1 + 3 * B * H, N1);
  }
  {
    int blocks = (N2 + 255) / 256;
    hipLaunchKernelGGL(rank_kernel, dim3(blocks), dim3(256), 0, stream,
                       h2, b2, Wg2, bg2,
                       s2, s2 + B * H, s2 + 2 * B * H, s2 + 3 * B * H, N2);
  }

  // fused head: agg@Wp -> LN -> SiLU -> FC1 -> SiLU -> FC2
  hipLaunchKernelGGL(finalize_kernel, dim3(B / 4), dim3(128), 0, stream,
                     ws, Wp0, bp0, Wp1, bp1, Wp2, bp2,
                     gamma, beta, W1, b1f, W2, b2f, (float*)d_out);
}

// Round 2
// 790.397 us; speedup vs baseline: 1.0119x; 1.0119x over previous
//
#include <hip/hip_runtime.h>
#include <hip/hip_bf16.h>
#include <math.h>

// Problem constants (match reference)
constexpr int H  = 128;   // hidden
constexpr int B  = 512;   // graphs
// Workspace layout per rank (floats):
//   [0,65536)        sum   [B][H]
//   [65536,131072)   gsum  [B][H]
//   [131072,196608)  max   [B][H]
//   [196608,197120)  cnt   [B]
constexpr int RANK_STRIDE = 3 * B * H + B;  // 197120 floats
constexpr int TOTAL_WS    = 3 * RANK_STRIDE;

constexpr int ROWS_PER_WAVE  = 128;
constexpr int ROWS_PER_BLOCK = 4 * ROWS_PER_WAVE;  // 4 waves/block = 512 rows

__device__ __forceinline__ float atomicMaxF(float* addr, float val) {
  // bit trick: int-max for >=0, uint-min for <0; buffer init to -inf
  if (val >= 0.f) {
    return __int_as_float(atomicMax((int*)addr, __float_as_int(val)));
  } else {
    return __uint_as_float(atomicMin((unsigned int*)addr, __float_as_uint(val)));
  }
}

__global__ __launch_bounds__(256) void init_ws_kernel(float* ws) {
  int i = blockIdx.x * blockDim.x + threadIdx.x;
  if (i >= TOTAL_WS) return;
  int o = i % RANK_STRIDE;
  bool ismax = (o >= 2 * B * H) && (o < 3 * B * H);
  ws[i] = ismax ? __int_as_float(0xFF800000) : 0.0f;  // -inf for max, 0 else
}

// Fused streaming kernel over all 3 ranks.
// Layout: lane l handles cols 4*(l&31)..+3; lanes 0..31 = even row of a pair,
// lanes 32..63 = odd row. One float4 load instruction fetches 2 full rows.
// Gate dot product: 5-step butterfly within each 32-lane half (2 rows/reduce).
// Segment accumulators (sum/gsum/max x 4 cols + cnt) live per-lane in VGPRs;
// per-lane `cur` + predicated flush handles boundaries; fast path for
// segment-uniform 64-row chunks is fully unrolled and branch-free.
__global__ __launch_bounds__(256) void rank_fused_kernel(
    const float* __restrict__ h0, const int* __restrict__ b0,
    const float* __restrict__ Wg0, const float* __restrict__ bg0, int N0, int nb0,
    const float* __restrict__ h1, const int* __restrict__ b1,
    const float* __restrict__ Wg1, const float* __restrict__ bg1, int N1, int nb1,
    const float* __restrict__ h2, const int* __restrict__ b2,
    const float* __restrict__ Wg2, const float* __restrict__ bg2, int N2,
    float* __restrict__ ws)
{
  const int blk = blockIdx.x;
  const float* h; const int* b; const float* Wg; const float* bg;
  float* base; int N; int lblk;
  if (blk < nb0) {
    h = h0; b = b0; Wg = Wg0; bg = bg0; base = ws;                   N = N0; lblk = blk;
  } else if (blk < nb0 + nb1) {
    h = h1; b = b1; Wg = Wg1; bg = bg1; base = ws + RANK_STRIDE;     N = N1; lblk = blk - nb0;
  } else {
    h = h2; b = b2; Wg = Wg2; bg = bg2; base = ws + 2 * RANK_STRIDE; N = N2; lblk = blk - nb0 - nb1;
  }

  const int lane = threadIdx.x & 63;
  const int wv   = threadIdx.x >> 6;
  const int half = lane >> 5;      // 0: even row of pair, 1: odd row
  const int c    = lane & 31;      // column group (4 floats)

  const int wstart = (lblk * 4 + wv) * ROWS_PER_WAVE;
  if (wstart >= N) return;
  const int wend = min(wstart + ROWS_PER_WAVE, N);

  float* __restrict__ sumb  = base;
  float* __restrict__ gsumb = base + B * H;
  float* __restrict__ maxb  = base + 2 * B * H;
  float* __restrict__ cntb  = base + 3 * B * H;

  const float4 wg  = ((const float4*)Wg)[c];
  const float  bgv = bg[0];

  // preload the wave's segment ids into 2 registers (coalesced, then shuffle)
  const int bv0 = b[min(wstart + lane, N - 1)];
  const int bv1 = b[min(wstart + 64 + lane, N - 1)];

  float4 s  = {0.f, 0.f, 0.f, 0.f};
  float4 gq = {0.f, 0.f, 0.f, 0.f};
  float4 m  = {-INFINITY, -INFINITY, -INFINITY, -INFINITY};
  int cnt = 0;
  int cur = -1;

  auto flushLane = [&]() {
    if (cur >= 0) {
      const int bi = cur * H + c * 4;
      atomicAdd(sumb + bi + 0, s.x);  atomicAdd(sumb + bi + 1, s.y);
      atomicAdd(sumb + bi + 2, s.z);  atomicAdd(sumb + bi + 3, s.w);
      atomicAdd(gsumb + bi + 0, gq.x); atomicAdd(gsumb + bi + 1, gq.y);
      atomicAdd(gsumb + bi + 2, gq.z); atomicAdd(gsumb + bi + 3, gq.w);
      atomicMaxF(maxb + bi + 0, m.x); atomicMaxF(maxb + bi + 1, m.y);
      atomicMaxF(maxb + bi + 2, m.z); atomicMaxF(maxb + bi + 3, m.w);
      if (c == 0 && cnt) atomicAdd(cntb + cur, (float)cnt);
      s = {0.f, 0.f, 0.f, 0.f};
      gq = {0.f, 0.f, 0.f, 0.f};
      m = {-INFINITY, -INFINITY, -INFINITY, -INFINITY};
      cnt = 0;
    }
  };

  auto gateOf = [&](float4 v) -> float {
    float p = fmaf(v.x, wg.x, fmaf(v.y, wg.y, fmaf(v.z, wg.z, v.w * wg.w)));
    p += __shfl_xor(p, 1);
    p += __shfl_xor(p, 2);
    p += __shfl_xor(p, 4);
    p += __shfl_xor(p, 8);
    p += __shfl_xor(p, 16);   // full row dot within each 32-lane half
    return 1.0f / (1.0f + __expf(-(p + bgv)));
  };

  auto accum = [&](float4 v, float gt) {
    s.x += v.x; s.y += v.y; s.z += v.z; s.w += v.w;
    gq.x = fmaf(gt, v.x, gq.x); gq.y = fmaf(gt, v.y, gq.y);
    gq.z = fmaf(gt, v.z, gq.z); gq.w = fmaf(gt, v.w, gq.w);
    m.x = fmaxf(m.x, v.x); m.y = fmaxf(m.y, v.y);
    m.z = fmaxf(m.z, v.z); m.w = fmaxf(m.w, v.w);
  };

  const float4* __restrict__ hp = (const float4*)h;

  int r = wstart;
  while (r + 64 <= wend) {
    const int bv = (r - wstart < 64) ? bv0 : bv1;
    const int sA = __shfl(bv, 0);
    const int sB = __shfl(bv, 63);
    if (sA == sB) {
      // fast path: whole 64-row chunk in one segment, branch-free
      if (sA != cur) { flushLane(); cur = sA; }
      #pragma unroll
      for (int g = 0; g < 4; ++g) {
        float4 v[8];
        #pragma unroll
        for (int i = 0; i < 8; ++i)
          v[i] = hp[(size_t)(r + g * 16 + 2 * i + half) * 32 + c];
        #pragma unroll
        for (int i = 0; i < 8; ++i) {
          const float gt = gateOf(v[i]);
          accum(v[i], gt);
        }
      }
      cnt += 32;  // 32 rows per half
    } else {
      // slow path: per-pair, per-lane segment tracking
      #pragma unroll 4
      for (int i = 0; i < 32; ++i) {
        const int seg = __shfl(bv, 2 * i + half);
        const float4 v = hp[(size_t)(r + 2 * i + half) * 32 + c];
        const float gt = gateOf(v);
        if (seg != cur) { flushLane(); cur = seg; }
        accum(v, gt);
        ++cnt;
      }
    }
    r += 64;
  }
  // tail pairs
  while (r + 2 <= wend) {
    const int o = r - wstart;
    const int bv = (o < 64) ? bv0 : bv1;
    const int seg = __shfl(bv, (o & 63) + half);
    const float4 v = hp[(size_t)(r + half) * 32 + c];
    const float gt = gateOf(v);
    if (seg != cur) { flushLane(); cur = seg; }
    accum(v, gt);
    ++cnt;
    r += 2;
  }
  // final single row (lower half only; both halves loaded the same row)
  if (r < wend) {
    const int o = r - wstart;
    const int bv = (o < 64) ? bv0 : bv1;
    const int seg = __shfl(bv, o & 63);
    const float4 v = hp[(size_t)r * 32 + c];
    const float gt = gateOf(v);
    if (half == 0) {
      if (seg != cur) { flushLane(); cur = seg; }
      accum(v, gt);
      ++cnt;
    }
  }
  flushLane();
}

__device__ __forceinline__ float siluf(float x) {
  return x / (1.0f + __expf(-x));
}

// 128 threads, 4 graphs per block (grid = B/4 = 128).
__global__ __launch_bounds__(128) void finalize_kernel(
    const float* __restrict__ ws,
    const float* __restrict__ Wp0, const float* __restrict__ bp0,
    const float* __restrict__ Wp1, const float* __restrict__ bp1,
    const float* __restrict__ Wp2, const float* __restrict__ bp2,
    const float* __restrict__ gamma, const float* __restrict__ beta,
    const float* __restrict__ W1, const float* __restrict__ b1f,
    const float* __restrict__ W2, const float* __restrict__ b2f,
    float* __restrict__ out)
{
  __shared__ float aggL[4][4 * H];   // 8 KB
  __shared__ float state[4][3 * H];  // 6 KB
  __shared__ float red[8];

  const int j = threadIdx.x;         // 0..127
  const int lane = j & 63;
  const int wv = j >> 6;             // 0..1
  const int gbase = blockIdx.x * 4;

  const float* Wp[3] = {Wp0, Wp1, Wp2};
  const float* bp[3] = {bp0, bp1, bp2};

  for (int k = 0; k < 3; ++k) {
    const float* sumb  = ws + k * RANK_STRIDE;
    const float* gsumb = sumb + B * H;
    const float* maxb  = sumb + 2 * B * H;
    const float* cntb  = sumb + 3 * B * H;

    for (int g = 0; g < 4; ++g) {
      const int bidx = gbase + g;
      const float cc = cntb[bidx];
      const float cm = fmaxf(cc, 1.0f);
      const float sv = sumb[bidx * H + j];
      const float mv = maxb[bidx * H + j];
      const float gv = gsumb[bidx * H + j];
      aggL[g][j]         = sv;
      aggL[g][H + j]     = sv / cm;
      aggL[g][2 * H + j] = (cc > 0.f) ? mv : 0.f;
      aggL[g][3 * H + j] = gv;
    }
    __syncthreads();

    const float bpv = bp[k][j];
    float r0 = bpv, r1 = bpv, r2 = bpv, r3 = bpv;
    const float* W = Wp[k];
    for (int i = 0; i < 4 * H; ++i) {
      const float w = W[i * H + j];        // coalesced; L2-resident
      r0 = fmaf(aggL[0][i], w, r0);        // LDS broadcast reads
      r1 = fmaf(aggL[1][i], w, r1);
      r2 = fmaf(aggL[2][i], w, r2);
      r3 = fmaf(aggL[3][i], w, r3);
    }
    state[0][k * H + j] = r0;
    state[1][k * H + j] = r1;
    state[2][k * H + j] = r2;
    state[3][k * H + j] = r3;
    __syncthreads();
  }

  // LayerNorm + SiLU per graph (384 elems, 3 per thread)
  for (int g = 0; g < 4; ++g) {
    const float v0 = state[g][j];
    const float v1 = state[g][H + j];
    const float v2 = state[g][2 * H + j];
    float ps = v0 + v1 + v2;
    float pq = v0 * v0 + v1 * v1 + v2 * v2;
    for (int mm = 1; mm < 64; mm <<= 1) {
      ps += __shfl_xor(ps, mm);
      pq += __shfl_xor(pq, mm);
    }
    if (lane == 0) { red[wv * 2] = ps; red[wv * 2 + 1] = pq; }
    __syncthreads();
    const float ts = red[0] + red[2];
    const float tq = red[1] + red[3];
    const float mu  = ts * (1.0f / 384.0f);
    const float var = tq * (1.0f / 384.0f) - mu * mu;
    const float inv = rsqrtf(var + 1e-5f);
    float x0 = (v0 - mu) * inv * gamma[j]         + beta[j];
    float x1 = (v1 - mu) * inv * gamma[H + j]     + beta[H + j];
    float x2 = (v2 - mu) * inv * gamma[2 * H + j] + beta[2 * H + j];
    state[g][j]         = siluf(x0);
    state[g][H + j]     = siluf(x1);
    state[g][2 * H + j] = siluf(x2);
    __syncthreads();
  }

  // FC1: x = silu(state @ W1 + b1f); weight load shared across 4 graphs
  const float b1v = b1f[j];
  float a0 = b1v, a1 = b1v, a2 = b1v, a3 = b1v;
  for (int i = 0; i < 3 * H; ++i) {
    const float w = W1[i * H + j];
    a0 = fmaf(state[0][i], w, a0);
    a1 = fmaf(state[1][i], w, a1);
    a2 = fmaf(state[2][i], w, a2);
    a3 = fmaf(state[3][i], w, a3);
  }
  a0 = siluf(a0); a1 = siluf(a1); a2 = siluf(a2); a3 = siluf(a3);

  // FC2: dot over 128
  const float w2 = W2[j];
  float p0 = a0 * w2, p1 = a1 * w2, p2 = a2 * w2, p3 = a3 * w2;
  for (int mm = 1; mm < 64; mm <<= 1) {
    p0 += __shfl_xor(p0, mm);
    p1 += __shfl_xor(p1, mm);
    p2 += __shfl_xor(p2, mm);
    p3 += __shfl_xor(p3, mm);
  }
  __syncthreads();  // red[] reuse
  if (lane == 0) {
    red[wv * 4 + 0] = p0; red[wv * 4 + 1] = p1;
    red[wv * 4 + 2] = p2; red[wv * 4 + 3] = p3;
  }
  __syncthreads();
  if (j < 4) out[gbase + j] = red[j] + red[4 + j] + b2f[0];
}

extern "C" void kernel_launch(void* const* d_in, const int* in_sizes, int n_in,
                              void* d_out, int out_size, void* d_ws, size_t ws_size,
                              hipStream_t stream) {
  const float* h0  = (const float*)d_in[0];
  const float* h1  = (const float*)d_in[1];
  const float* h2  = (const float*)d_in[2];
  const int*   b0  = (const int*)d_in[3];
  const int*   b1  = (const int*)d_in[4];
  const int*   b2  = (const int*)d_in[5];
  const float* Wg0 = (const float*)d_in[6];
  const float* bg0 = (const float*)d_in[7];
  const float* Wg1 = (const float*)d_in[8];
  const float* bg1 = (const float*)d_in[9];
  const float* Wg2 = (const float*)d_in[10];
  const float* bg2 = (const float*)d_in[11];
  const float* Wp0 = (const float*)d_in[12];
  const float* bp0 = (const float*)d_in[13];
  const float* Wp1 = (const float*)d_in[14];
  const float* bp1 = (const float*)d_in[15];
  const float* Wp2 = (const float*)d_in[16];
  const float* bp2 = (const float*)d_in[17];
  const float* gamma = (const float*)d_in[18];
  const float* beta  = (const float*)d_in[19];
  const float* W1  = (const float*)d_in[20];
  const float* b1f = (const float*)d_in[21];
  const float* W2  = (const float*)d_in[22];
  const float* b2f = (const float*)d_in[23];

  const int N0 = in_sizes[3];
  const int N1 = in_sizes[4];
  const int N2 = in_sizes[5];

  float* ws = (float*)d_ws;

  // init workspace (sums/cnt = 0, max = -inf)
  {
    int blocks = (TOTAL_WS + 255) / 256;
    hipLaunchKernelGGL(init_ws_kernel, dim3(blocks), dim3(256), 0, stream, ws);
  }

  // fused streaming pass over all 3 ranks
  const int nb0 = (N0 + ROWS_PER_BLOCK - 1) / ROWS_PER_BLOCK;
  const int nb1 = (N1 + ROWS_PER_BLOCK - 1) / ROWS_PER_BLOCK;
  const int nb2 = (N2 + ROWS_PER_BLOCK - 1) / ROWS_PER_BLOCK;
  hipLaunchKernelGGL(rank_fused_kernel, dim3(nb0 + nb1 + nb2), dim3(256), 0, stream,
                     h0, b0, Wg0, bg0, N0, nb0,
                     h1, b1, Wg1, bg1, N1, nb1,
                     h2, b2, Wg2, bg2, N2,
                     ws);

  // fused head: agg@Wp -> LN -> SiLU -> FC1 -> SiLU -> FC2
  hipLaunchKernelGGL(finalize_kernel, dim3(B / 4), dim3(128), 0, stream,
                     ws, Wp0, bp0, Wp1, bp1, Wp2, bp2,
                     gamma, beta, W1, b1f, W2, b2f, (float*)d_out);
}